// Round 10
// baseline (282.402 us; speedup 1.0000x reference)
//
#include <hip/hip_runtime.h>
#include <hip/hip_bf16.h>
#include <math.h>

#define B_ 8
#define T_ 1024
#define D_ 512
#define PRED 256
#define TP (T_ + PRED)
#define NH 8
#define DH 64
#define DFF 2048
#define CO 64
#define KSEL 8

typedef __hip_bfloat16 bf16;
using bf16x8 = __attribute__((ext_vector_type(8))) short;
using f32x4  = __attribute__((ext_vector_type(4))) float;

__device__ __forceinline__ void gload_lds16(const void* gp, void* lp) {
  __builtin_amdgcn_global_load_lds(
      (const __attribute__((address_space(1))) void*)gp,
      (__attribute__((address_space(3))) void*)lp, 16, 0, 0);
}

// counted vmem wait (N = loads allowed to stay in flight)
template <int N>
__device__ __forceinline__ void vm_wait() {
  if constexpr (N == 0)      asm volatile("s_waitcnt vmcnt(0)" ::: "memory");
  else if constexpr (N == 2) asm volatile("s_waitcnt vmcnt(2)" ::: "memory");
  else if constexpr (N == 4) asm volatile("s_waitcnt vmcnt(4)" ::: "memory");
  else if constexpr (N == 6) asm volatile("s_waitcnt vmcnt(6)" ::: "memory");
  else if constexpr (N == 8) asm volatile("s_waitcnt vmcnt(8)" ::: "memory");
  else static_assert(N == 0, "unsupported vmcnt literal");
}

// ---------------- transpose res (b,T,D) -> resT (b,D,T) ----------------
__global__ __launch_bounds__(256) void k_transpose(const float* __restrict__ in, float* __restrict__ out) {
  __shared__ float tile[32][33];
  const int b = blockIdx.z;
  const int d0 = blockIdx.x * 32, t0 = blockIdx.y * 32;
  const int tx = threadIdx.x, ty = threadIdx.y;
  const float* src = in + ((size_t)b * T_ + t0) * D_ + d0;
#pragma unroll
  for (int i = 0; i < 32; i += 8) tile[ty + i][tx] = src[(size_t)(ty + i) * D_ + tx];
  __syncthreads();
  float* dst = out + ((size_t)b * D_ + d0) * T_ + t0;
#pragma unroll
  for (int i = 0; i < 32; i += 8) dst[(size_t)(ty + i) * T_ + tx] = tile[tx][ty + i];
}

// ---------------- 1024-pt real FFT per (b,d) + top-8 bins ----------------
__global__ __launch_bounds__(256) void k_fft_topk(const float* __restrict__ xt, float* __restrict__ comp) {
  __shared__ float2 bA[512], bB[512], tw[256];
  __shared__ float xre[512], xim[512], mag2[512];
  __shared__ float wvv[4];
  __shared__ int wkk[4];
  __shared__ int selk[KSEL];
  const int j = threadIdx.x;
  const int bd = blockIdx.x;
  {
    float ang = -(6.283185307179586f / 512.0f) * (float)j;
    float sn, cs;
    sincosf(ang, &sn, &cs);
    tw[j] = make_float2(cs, sn);
  }
  const float4 v4 = ((const float4*)(xt + (size_t)bd * 1024))[j];
  bA[2 * j] = make_float2(v4.x, v4.y);
  bA[2 * j + 1] = make_float2(v4.z, v4.w);
  __syncthreads();
#pragma unroll
  for (int st = 0; st < 9; ++st) {
    const int s = 1 << st;
    const int p = j >> st;
    const int q = j & (s - 1);
    const int m = 256 >> st;
    float2 a, b2;
    if ((st & 1) == 0) { a = bA[q + s * p]; b2 = bA[q + s * (p + m)]; }
    else               { a = bB[q + s * p]; b2 = bB[q + s * (p + m)]; }
    const float2 w = tw[p << st];
    float2 d0 = make_float2(a.x + b2.x, a.y + b2.y);
    const float ex = a.x - b2.x, ey = a.y - b2.y;
    float2 d1 = make_float2(ex * w.x - ey * w.y, ex * w.y + ey * w.x);
    if ((st & 1) == 0) { bB[q + s * 2 * p] = d0; bB[q + s * (2 * p + 1)] = d1; }
    else               { bA[q + s * 2 * p] = d0; bA[q + s * (2 * p + 1)] = d1; }
    __syncthreads();
  }
#pragma unroll
  for (int u = 0; u < 2; ++u) {
    const int k = (u == 0) ? (j + 1) : (j + 257);
    if (k <= 511) {
      const float2 zk = bB[k & 511];
      const float2 zm = bB[(512 - k) & 511];
      const float Ex = 0.5f * (zk.x + zm.x), Ey = 0.5f * (zk.y - zm.y);
      const float Ox = 0.5f * (zk.y + zm.y), Oy = 0.5f * (zm.x - zk.x);
      float sn, cs;
      sincosf(-(6.283185307179586f / 1024.0f) * (float)k, &sn, &cs);
      const float Xr = Ex + cs * Ox - sn * Oy;
      const float Xi = Ey + cs * Oy + sn * Ox;
      xre[k] = Xr; xim[k] = Xi; mag2[k] = Xr * Xr + Xi * Xi;
    }
  }
  if (j == 0) mag2[0] = -1.0f;
  __syncthreads();
  const int lane = j & 63, wvi = j >> 6;
  for (int r = 0; r < KSEL; ++r) {
    float bv = mag2[j];
    int bk = j;
    const float v2 = mag2[j + 256];
    if (v2 > bv) { bv = v2; bk = j + 256; }
#pragma unroll
    for (int off = 32; off; off >>= 1) {
      const float ov = __shfl_down(bv, off);
      const int ok = __shfl_down(bk, off);
      if (ov > bv || (ov == bv && ok < bk)) { bv = ov; bk = ok; }
    }
    if (lane == 0) { wvv[wvi] = bv; wkk[wvi] = bk; }
    __syncthreads();
    if (j == 0) {
      float fv = wvv[0];
      int fk = wkk[0];
#pragma unroll
      for (int i = 1; i < 4; i++)
        if (wvv[i] > fv || (wvv[i] == fv && wkk[i] < fk)) { fv = wvv[i]; fk = wkk[i]; }
      selk[r] = fk;
      mag2[fk] = -2.0f;
    }
    __syncthreads();
  }
  if (j < KSEL) {
    const int k = selk[j];
    const float re = xre[k], im = xim[k];
    float* o = comp + (size_t)bd * 24 + j * 3;
    o[0] = 2.0f * sqrtf(re * re + im * im) * (1.0f / 1024.0f);
    o[1] = (float)k;
    o[2] = atan2f(im, re);
  }
}

// ---------------- season synthesis + res1 = res - season ----------------
__global__ __launch_bounds__(512) void k_season(const float* __restrict__ comp, const float* __restrict__ res,
                                                float* __restrict__ season, bf16* __restrict__ res1b,
                                                bf16* __restrict__ seasb) {
  const int d = threadIdx.x;
  const int b = blockIdx.y;
  const int t0 = blockIdx.x * 5;
  float a_[8], kf_[8], ph_[8];
  const float* c = comp + ((size_t)b * 512 + d) * 24;
#pragma unroll
  for (int i = 0; i < 8; i++) { a_[i] = c[3 * i]; kf_[i] = c[3 * i + 1]; ph_[i] = c[3 * i + 2]; }
#pragma unroll
  for (int tt = 0; tt < 5; ++tt) {
    const int t = t0 + tt;
    float acc = 0.0f;
#pragma unroll
    for (int i = 0; i < 8; i++) {
      float fr = kf_[i] * (float)t * (1.0f / 1024.0f);
      fr -= floorf(fr);
      acc += a_[i] * __cosf(fmaf(6.283185307179586f, fr, ph_[i]));
    }
    season[((size_t)b * TP + t) * D_ + d] = acc;
    if (t < T_) {
      const float rr = res[((size_t)b * T_ + t) * D_ + d] - acc;
      res1b[((size_t)b * T_ + t) * D_ + d] = __float2bfloat16(rr);
      seasb[((size_t)b * T_ + t) * D_ + d] = __float2bfloat16(acc);
    }
  }
}

// ---------------- fused f32 -> bf16 for all 6 weight tensors ----------------
#define CVT_TOTAL 2686976
__global__ __launch_bounds__(256) void k_cvt_all(const float* __restrict__ s0, const float* __restrict__ s1,
                                                 const float* __restrict__ s2_, const float* __restrict__ s3,
                                                 const float* __restrict__ s4, const float* __restrict__ s5,
                                                 bf16* __restrict__ dst) {
  const int i = (blockIdx.x * 256 + threadIdx.x) * 4;
  if (i >= CVT_TOTAL) return;
  const float* src;
  int off;
  if (i < 262144)       { src = s0;  off = i; }
  else if (i < 524288)  { src = s1;  off = i - 262144; }
  else if (i < 1572864) { src = s2_; off = i - 524288; }
  else if (i < 2621440) { src = s3;  off = i - 1572864; }
  else if (i < 2654208) { src = s4;  off = i - 2621440; }
  else                  { src = s5;  off = i - 2654208; }
  const float4 v = *(const float4*)(src + off);
  bf16* o = dst + i;
  o[0] = __float2bfloat16(v.x); o[1] = __float2bfloat16(v.y);
  o[2] = __float2bfloat16(v.z); o[3] = __float2bfloat16(v.w);
}

// ---------------- growth exp-smooth blocked scan ----------------
__global__ __launch_bounds__(1024) void k_growth_scan2(const float* __restrict__ v, const float* __restrict__ z0,
                                                       const float* __restrict__ sw, const float* __restrict__ v0,
                                                       bf16* __restrict__ s2) {
  const int b = blockIdx.x >> 3;
  const int col = (blockIdx.x & 7) * 64 + (threadIdx.x & 63);
  const int w = threadIdx.x >> 6;
  const float alpha = 1.0f / (1.0f + expf(-sw[col >> 6]));
  const float om = 1.0f - alpha;
  float a64 = alpha;
#pragma unroll
  for (int i = 0; i < 6; i++) a64 *= a64;
  const float* vp = v + (size_t)b * T_ * D_ + col;
  float vprev = (w == 0) ? z0[col] : vp[(size_t)(64 * w - 1) * D_];
  float sloc = 0.0f;
#pragma unroll 8
  for (int j = 0; j < 64; j++) {
    const float nv = vp[(size_t)(64 * w + j) * D_];
    sloc = alpha * sloc + om * (nv - vprev);
    vprev = nv;
  }
  __shared__ float lb[16][64], lc[16][64];
  lb[w][threadIdx.x & 63] = sloc;
  __syncthreads();
  if (w == 0) {
    float s = v0[col];
#pragma unroll
    for (int k = 0; k < 16; k++) { lc[k][threadIdx.x & 63] = s; s = a64 * s + lb[k][threadIdx.x & 63]; }
  }
  __syncthreads();
  float s = lc[w][threadIdx.x & 63];
  vprev = (w == 0) ? z0[col] : vp[(size_t)(64 * w - 1) * D_];
  bf16* op = s2 + (size_t)b * (T_ + 1) * D_ + col;
  if (w == 0) op[0] = __float2bfloat16(v0[col]);
#pragma unroll 8
  for (int j = 0; j < 64; j++) {
    const float nv = vp[(size_t)(64 * w + j) * D_];
    s = alpha * s + om * (nv - vprev);
    vprev = nv;
    op[(size_t)(64 * w + j + 1) * D_] = __float2bfloat16(s);
  }
}

// ---------------- level exp-smooth blocked scan ----------------
__global__ __launch_bounds__(1024) void k_level_scan2(const float* __restrict__ level, const float* __restrict__ gp,
                                                      const float* __restrict__ sp, const float* __restrict__ sw,
                                                      const float* __restrict__ v0, float* __restrict__ out) {
  const int b = blockIdx.x;
  const int w = threadIdx.x >> 6;
  const int c = threadIdx.x & 63;
  const float alpha = 1.0f / (1.0f + expf(-sw[c]));
  const float om = 1.0f - alpha;
  float a64 = alpha;
#pragma unroll
  for (int i = 0; i < 6; i++) a64 *= a64;
  const size_t base = ((size_t)b * T_ + 64 * w) * CO + c;
  float sloc = 0.0f;
#pragma unroll 8
  for (int j = 0; j < 64; j++) {
    const size_t idx = base + (size_t)j * CO;
    const float u = om * (level[idx] - sp[idx]) + alpha * gp[idx];
    out[idx] = u;
    sloc = alpha * sloc + u;
  }
  __shared__ float lb[16][64], lc[16][64];
  lb[w][c] = sloc;
  __syncthreads();
  if (w == 0) {
    float s = v0[c];
#pragma unroll
    for (int k = 0; k < 16; k++) { lc[k][c] = s; s = a64 * s + lb[k][c]; }
  }
  __syncthreads();
  float s = lc[w][c];
#pragma unroll 8
  for (int j = 0; j < 64; j++) {
    const size_t idx = base + (size_t)j * CO;
    s = alpha * s + out[idx];
    out[idx] = s;
  }
}

// ---------------- layer norm over D=512 ----------------
template <int MODE>
__global__ __launch_bounds__(128) void k_ln(const float* __restrict__ x1, const float* __restrict__ x2,
                                            const float* __restrict__ x3, const float* __restrict__ g,
                                            const float* __restrict__ be, float* __restrict__ outF,
                                            bf16* __restrict__ outB) {
  const int m = blockIdx.x, tid = threadIdx.x;
  const int b = m >> 10;
  float4 v = ((const float4*)(x1 + (size_t)m * D_))[tid];
  if (MODE == 0) {
    const float4 se = ((const float4*)(x2 + ((size_t)(m + b * PRED)) * D_))[tid];
    const float4 gr = ((const float4*)(x3 + ((size_t)(m + b + 1)) * D_))[tid];
    v.x -= se.x + gr.x; v.y -= se.y + gr.y; v.z -= se.z + gr.z; v.w -= se.w + gr.w;
  }
  float s = v.x + v.y + v.z + v.w;
  float s2 = v.x * v.x + v.y * v.y + v.z * v.z + v.w * v.w;
#pragma unroll
  for (int off = 32; off; off >>= 1) { s += __shfl_down(s, off); s2 += __shfl_down(s2, off); }
  __shared__ float p1[2], p2[2];
  if ((tid & 63) == 0) { p1[tid >> 6] = s; p2[tid >> 6] = s2; }
  __syncthreads();
  const float S = p1[0] + p1[1], S2 = p2[0] + p2[1];
  const float mu = S * (1.0f / 512.0f);
  const float rs = rsqrtf(fmaxf(S2 * (1.0f / 512.0f) - mu * mu, 0.0f) + 1e-5f);
  const float4 gg = ((const float4*)g)[tid], bb = ((const float4*)be)[tid];
  float4 o;
  o.x = (v.x - mu) * rs * gg.x + bb.x;
  o.y = (v.y - mu) * rs * gg.y + bb.y;
  o.z = (v.z - mu) * rs * gg.z + bb.z;
  o.w = (v.w - mu) * rs * gg.w + bb.w;
  ((float4*)(outF + (size_t)m * D_))[tid] = o;
  if (MODE == 0) {
    bf16* ob = outB + (size_t)m * D_ + tid * 4;
    ob[0] = __float2bfloat16(o.x); ob[1] = __float2bfloat16(o.y);
    ob[2] = __float2bfloat16(o.z); ob[3] = __float2bfloat16(o.w);
  }
}

// ---------------- FF1: h = sigmoid(res2b @ ff_w1^T) — A-resident-in-LDS GEMM ----------------
// Block = 64-row A panel (held in LDS, 64KB, swizzled) x 1024 n-cols (8 tiles of 128).
// B streamed in 128x32 tiles (8KB), triple-buffered, 2-deep prefetch, ONE barrier/phase.
// 128 phases/block -> long steady-state pipeline (vs 16 transient-dominated iters before).
__global__ __launch_bounds__(256) void k_ff1(const bf16* __restrict__ A, const bf16* __restrict__ Bw,
                                             bf16* __restrict__ outB) {
  constexpr int Kc = 512, Nc = 2048, P = 128;  // P = NTILE(8) * KT(16)
  __shared__ bf16 lsA[64 * 512];     // 64KB resident A panel
  __shared__ bf16 lsB[3][128 * 32];  // 3 x 8KB B stream buffers
  const int tid = threadIdx.x;
  const int w = tid >> 6, lane = tid & 63;
  const int ng = blockIdx.x, tm = blockIdx.y;
  const int wr = w >> 1, wc = w & 1;
  const int r16 = lane & 15, hi = lane >> 4;

  // B staging decode (BK=32 swizzle scheme, identical to k_gemm)
  const int sr = lane >> 3, cs = lane & 7;
  const int bidx = cs ^ (sr & 7);
  const int srowoff = sr * 2 + (bidx >> 2);
  const int scoloff = (bidx & 3) * 8;

  auto stageB = [&](int p, int sel) {
    const int nt = p >> 4, kt = p & 15;
#pragma unroll
    for (int q = 0; q < 2; q++) {
      const int g = w * 2 + q;
      const int n = ng * 1024 + nt * 128 + g * 16 + srowoff;
      gload_lds16(Bw + (size_t)n * Kc + kt * 32 + scoloff, &lsB[sel][g * 512]);
    }
  };

  // prologue: A panel once (1 row = 1 gload call; slot l holds chunk l^(r&7)), B(0), B(1)
#pragma unroll
  for (int q = 0; q < 16; q++) {
    const int r = w * 16 + q;
    const int m = tm * 64 + r;
    gload_lds16(A + (size_t)m * Kc + ((lane ^ (r & 7)) << 3), &lsA[r * 512]);
  }
  stageB(0, 0);
  stageB(1, 1);
  vm_wait<2>();   // A + B(0) done; B(1) stays in flight
  __builtin_amdgcn_sched_barrier(0);
  __builtin_amdgcn_s_barrier();
  __builtin_amdgcn_sched_barrier(0);

  const f32x4 fz = {0.f, 0.f, 0.f, 0.f};
  f32x4 acc[2][4];
#pragma unroll
  for (int i = 0; i < 2; i++)
#pragma unroll
    for (int jj = 0; jj < 4; jj++) acc[i][jj] = fz;

  for (int p = 0; p < P; ++p) {
    const int sel = p % 3;
    const int kt = p & 15;
    if (p + 2 < P) stageB(p + 2, (p + 2) % 3);  // write buf freed by barrier after phase p-1
    bf16x8 af[2], bfv[4];
#pragma unroll
    for (int i = 0; i < 2; i++) {
      const int row = wr * 32 + i * 16 + r16;
      const int cc = kt * 4 + hi;
      af[i] = *(const bf16x8*)&lsA[row * 512 + ((cc ^ (row & 7)) << 3)];
    }
#pragma unroll
    for (int jj = 0; jj < 4; jj++) {
      const int row = wc * 64 + jj * 16 + r16;
      const int g = row >> 4, rr = row & 15, sr2 = rr >> 1;
      const int idx = ((rr & 1) << 2) | hi;
      bfv[jj] = *(const bf16x8*)&lsB[sel][g * 512 + sr2 * 64 + ((idx ^ (sr2 & 7)) << 3)];
    }
#pragma unroll
    for (int i = 0; i < 2; i++)
#pragma unroll
      for (int jj = 0; jj < 4; jj++)
        acc[i][jj] = __builtin_amdgcn_mfma_f32_16x16x32_bf16(af[i], bfv[jj], acc[i][jj], 0, 0, 0);
    if (kt == 15) {  // n-tile complete: sigmoid epilogue, reset acc
      const int nt = p >> 4;
#pragma unroll
      for (int i = 0; i < 2; i++)
#pragma unroll
        for (int r = 0; r < 4; r++) {
          const int m = tm * 64 + wr * 32 + i * 16 + hi * 4 + r;
#pragma unroll
          for (int jj = 0; jj < 4; jj++) {
            const int n = ng * 1024 + nt * 128 + wc * 64 + jj * 16 + r16;
            outB[(size_t)m * Nc + n] = __float2bfloat16(1.0f / (1.0f + __expf(-acc[i][jj][r])));
            acc[i][jj][r] = 0.0f;
          }
        }
    }
    if (p + 1 < P) {
      if (p + 2 < P) vm_wait<2>(); else vm_wait<0>();  // B(p+1) ready; B(p+2) in flight
      __builtin_amdgcn_sched_barrier(0);
      __builtin_amdgcn_s_barrier();   // readiness of buf p+1 AND read-protection of buf p
      __builtin_amdgcn_sched_barrier(0);
    }
  }
}

// ---------------- bf16 MFMA GEMM, swizzled LDS + counted-vmcnt pipeline ----------------
template <int BM, int BN, int BK, int EPI>
__global__ __launch_bounds__(256) void k_gemm(const bf16* __restrict__ A, const bf16* __restrict__ Bw,
                                              const float* __restrict__ bias, float* outF, bf16* __restrict__ outB,
                                              const float* resid, const int M, const int N, const int K,
                                              const int extra) {
  constexpr int WC = (BN >= 128) ? 2 : 1;
  constexpr int WR = 4 / WC;
  constexpr int FM = BM / (WR * 16);
  constexpr int FN = BN / (WC * 16);
  constexpr int RPC = 512 / BK;
  constexpr int LA = (BM / RPC) / 4, LB = (BN / RPC) / 4;
  constexpr int KK = BK / 32;
  constexpr int TLOADS = LA + LB;
  static_assert(LA >= 1 && LB >= 1, "tile too small for staging split");
  __shared__ bf16 lsA[2][BM * BK];
  __shared__ bf16 lsB[2][BN * BK];
  const int tid = threadIdx.x;
  const int w = tid >> 6, lane = tid & 63;
  const int tn = blockIdx.x, tm = blockIdx.y;
  const int wr = w / WC, wc = w % WC;
  const int r16 = lane & 15, hi = lane >> 4;

  int srowoff, scoloff;
  if constexpr (BK == 64) {
    const int rr = lane >> 3, cs = lane & 7;
    srowoff = rr;
    scoloff = (cs ^ rr) * 8;
  } else {
    const int sr = lane >> 3, cs = lane & 7;
    const int idx = cs ^ (sr & 7);
    srowoff = sr * 2 + (idx >> 2);
    scoloff = (idx & 3) * 8;
  }

  const f32x4 fzero = {0.f, 0.f, 0.f, 0.f};
  f32x4 acc[FM][FN];
#pragma unroll
  for (int i = 0; i < FM; i++)
#pragma unroll
    for (int jj = 0; jj < FN; jj++) acc[i][jj] = fzero;

  const int NT = K / BK;

  auto stage = [&](int kt, int sel) {
#pragma unroll
    for (int q = 0; q < LA; q++) {
      const int g = w * LA + q;
      int m = tm * BM + g * RPC + srowoff;
      if (m > M - 1) m = M - 1;
      m += (m >> 10) * extra;
      gload_lds16(A + (size_t)m * K + (size_t)kt * BK + scoloff, &lsA[sel][g * 512]);
    }
#pragma unroll
    for (int q = 0; q < LB; q++) {
      const int g = w * LB + q;
      const int n = tn * BN + g * RPC + srowoff;
      gload_lds16(Bw + (size_t)n * K + (size_t)kt * BK + scoloff, &lsB[sel][g * 512]);
    }
  };

  auto frag = [&](const bf16* ls, int row, int cc) -> bf16x8 {
    if constexpr (BK == 64) {
      const int g = row >> 3, rr = row & 7;
      return *(const bf16x8*)&ls[g * 512 + rr * 64 + ((cc ^ rr) << 3)];
    } else {
      const int g = row >> 4, rr = row & 15, sr = rr >> 1;
      const int idx = ((rr & 1) << 2) | cc;
      return *(const bf16x8*)&ls[g * 512 + sr * 64 + ((idx ^ (sr & 7)) << 3)];
    }
  };

  stage(0, 0);
  for (int kt = 0; kt < NT; ++kt) {
    const int sel = kt & 1;
    if (kt + 1 < NT) {
      stage(kt + 1, sel ^ 1);
      vm_wait<TLOADS>();
    } else {
      vm_wait<0>();
    }
    __builtin_amdgcn_sched_barrier(0);
    __builtin_amdgcn_s_barrier();
    __builtin_amdgcn_sched_barrier(0);
#pragma unroll
    for (int kk = 0; kk < KK; ++kk) {
      bf16x8 af[FM], bfv[FN];
#pragma unroll
      for (int i = 0; i < FM; i++)
        af[i] = frag(lsA[sel], wr * (FM * 16) + i * 16 + r16, kk * 4 + hi);
#pragma unroll
      for (int jj = 0; jj < FN; jj++)
        bfv[jj] = frag(lsB[sel], wc * (FN * 16) + jj * 16 + r16, kk * 4 + hi);
#pragma unroll
      for (int i = 0; i < FM; i++)
#pragma unroll
        for (int jj = 0; jj < FN; jj++)
          acc[i][jj] = __builtin_amdgcn_mfma_f32_16x16x32_bf16(af[i], bfv[jj], acc[i][jj], 0, 0, 0);
    }
    if (kt + 1 < NT) {
      __builtin_amdgcn_sched_barrier(0);
      __builtin_amdgcn_s_barrier();
      __builtin_amdgcn_sched_barrier(0);
    }
  }

#pragma unroll
  for (int i = 0; i < FM; i++) {
#pragma unroll
    for (int r = 0; r < 4; r++) {
      const int m = tm * BM + wr * (FM * 16) + i * 16 + hi * 4 + r;
      if (m < M) {
#pragma unroll
        for (int jj = 0; jj < FN; jj++) {
          const int n = tn * BN + wc * (FN * 16) + jj * 16 + r16;
          float x = acc[i][jj][r];
          if (bias) x += bias[n];
          const size_t idx = (size_t)m * N + n;
          if (EPI == 0) {
            outF[idx] = x;
          } else if (EPI == 1) {
            outF[idx] = x;
            outB[idx] = __float2bfloat16(x);
          } else if (EPI == 2) {
            outB[idx] = __float2bfloat16(1.0f / (1.0f + __expf(-x)));
          } else {
            outF[idx] = x + resid[idx];
          }
        }
      }
    }
  }
}

// ---------------- workspace layout ----------------
#define MB (size_t)(1u << 20)
static const size_t OFF_A = 0;
static const size_t OFF_C = 32 * MB;
static const size_t OFF_D = 40 * MB;
static const size_t OFF_E = 48 * MB;
static const size_t OFF_F = 54 * MB;
static const size_t OFF_G = 63 * MB;
static const size_t OFF_H = 72 * MB;
static const size_t OFF_J = 88 * MB;
static const size_t OFF_K = 89 * MB;
static const size_t OFF_K2 = 91 * MB;

#define W_IN 0
#define W_OUT 262144
#define W_FF1 524288
#define W_FF2 1572864
#define W_GW 2621440
#define W_SW2 2654208

extern "C" void kernel_launch(void* const* d_in, const int* in_sizes, int n_in, void* d_out, int out_size,
                              void* d_ws, size_t ws_size, hipStream_t stream) {
  (void)in_sizes; (void)n_in; (void)out_size; (void)ws_size;
  const float* res = (const float*)d_in[0];
  const float* level = (const float*)d_in[1];
  const float* gl_z0 = (const float*)d_in[2];
  const float* gl_in_w = (const float*)d_in[3];
  const float* gl_in_b = (const float*)d_in[4];
  const float* gl_sw = (const float*)d_in[5];
  const float* gl_v0 = (const float*)d_in[6];
  const float* gl_out_w = (const float*)d_in[7];
  const float* gl_out_b = (const float*)d_in[8];
  const float* ll_sw = (const float*)d_in[9];
  const float* ll_v0 = (const float*)d_in[10];
  const float* ll_gw = (const float*)d_in[11];
  const float* ll_gb = (const float*)d_in[12];
  const float* ll_sw2 = (const float*)d_in[13];
  const float* ll_sb = (const float*)d_in[14];
  const float* ff_w1 = (const float*)d_in[15];
  const float* ff_w2 = (const float*)d_in[16];
  const float* n1_g = (const float*)d_in[17];
  const float* n1_b = (const float*)d_in[18];
  const float* n2_g = (const float*)d_in[19];
  const float* n2_b = (const float*)d_in[20];

  char* ws = (char*)d_ws;
  float* resT = (float*)(ws + OFF_A);
  float* vbuf = (float*)(ws + OFF_A);
  bf16* hbuf = (bf16*)(ws + OFF_A);
  bf16* res1b = (bf16*)(ws + OFF_C);
  bf16* res2b = (bf16*)(ws + OFF_C);
  bf16* seasb = (bf16*)(ws + OFF_D);
  bf16* wE = (bf16*)(ws + OFF_E);
  bf16* s2b = (bf16*)(ws + OFF_F);
  bf16* grob = (bf16*)(ws + OFF_G);
  float* res2f = (float*)(ws + OFF_H);
  float* comp = (float*)(ws + OFF_J);
  float* gproj = (float*)(ws + OFF_K);
  float* sproj = (float*)(ws + OFF_K2);

  float* o_res = (float*)d_out;
  float* o_level = o_res + 4194304;
  float* o_growth = o_level + 524288;
  float* o_season = o_growth + 4198400;

  k_transpose<<<dim3(16, 32, 8), dim3(32, 8), 0, stream>>>(res, resT);
  k_fft_topk<<<4096, 256, 0, stream>>>(resT, comp);
  k_season<<<dim3(256, 8), 512, 0, stream>>>(comp, res, o_season, res1b, seasb);
  k_cvt_all<<<(CVT_TOTAL / 4 + 255) / 256, 256, 0, stream>>>(gl_in_w, gl_out_w, ff_w1, ff_w2, ll_gw, ll_sw2, wE);
  // v = res1 @ gl_in_w^T + b
  k_gemm<64, 128, 64, 0><<<dim3(4, 128), 256, 0, stream>>>(res1b, wE + W_IN, gl_in_b, vbuf, nullptr, nullptr, 8192, 512, 512, 0);
  k_growth_scan2<<<64, 1024, 0, stream>>>(vbuf, gl_z0, gl_sw, gl_v0, s2b);
  // growth = s2 @ gl_out_w^T + b
  k_gemm<64, 128, 64, 1><<<dim3(4, 129), 256, 0, stream>>>(s2b, wE + W_OUT, gl_out_b, o_growth, grob, nullptr, 8200, 512, 512, 0);
  k_ln<0><<<8192, 128, 0, stream>>>(res, o_season, o_growth, n1_g, n1_b, res2f, res2b);
  // FF1: A-resident pipeline, grid (2 n-groups, 128 m-panels)
  k_ff1<<<dim3(2, 128), 256, 0, stream>>>(res2b, wE + W_FF1, hbuf);
  // FF2: 64x128 BK=64, K=2048
  k_gemm<64, 128, 64, 3><<<dim3(4, 128), 256, 0, stream>>>(hbuf, wE + W_FF2, nullptr, res2f, nullptr, res2f, 8192, 512, 2048, 0);
  k_ln<1><<<8192, 128, 0, stream>>>(res2f, nullptr, nullptr, n2_g, n2_b, o_res, nullptr);
  // gproj/sproj: 64x64 BK=64
  k_gemm<64, 64, 64, 0><<<dim3(1, 128), 256, 0, stream>>>(grob, wE + W_GW, ll_gb, gproj, nullptr, nullptr, 8192, 64, 512, 1);
  k_gemm<64, 64, 64, 0><<<dim3(1, 128), 256, 0, stream>>>(seasb, wE + W_SW2, ll_sb, sproj, nullptr, nullptr, 8192, 64, 512, 0);
  k_level_scan2<<<8, 1024, 0, stream>>>(level, gproj, sproj, ll_sw, ll_v0, o_level);
}

// Round 11
// 239.805 us; speedup vs baseline: 1.1776x; 1.1776x over previous
//
#include <hip/hip_runtime.h>
#include <hip/hip_bf16.h>
#include <math.h>

#define B_ 8
#define T_ 1024
#define D_ 512
#define PRED 256
#define TP (T_ + PRED)
#define NH 8
#define DH 64
#define DFF 2048
#define CO 64
#define KSEL 8

typedef __hip_bfloat16 bf16;
using bf16x8 = __attribute__((ext_vector_type(8))) short;
using f32x4  = __attribute__((ext_vector_type(4))) float;

__device__ __forceinline__ void gload_lds16(const void* gp, void* lp) {
  __builtin_amdgcn_global_load_lds(
      (const __attribute__((address_space(1))) void*)gp,
      (__attribute__((address_space(3))) void*)lp, 16, 0, 0);
}

// counted vmem wait (N = loads allowed to stay in flight)
template <int N>
__device__ __forceinline__ void vm_wait() {
  if constexpr (N == 0)      asm volatile("s_waitcnt vmcnt(0)" ::: "memory");
  else if constexpr (N == 2) asm volatile("s_waitcnt vmcnt(2)" ::: "memory");
  else if constexpr (N == 4) asm volatile("s_waitcnt vmcnt(4)" ::: "memory");
  else if constexpr (N == 6) asm volatile("s_waitcnt vmcnt(6)" ::: "memory");
  else if constexpr (N == 8) asm volatile("s_waitcnt vmcnt(8)" ::: "memory");
  else static_assert(N == 0, "unsupported vmcnt literal");
}

// ---------------- transpose res (b,T,D) -> resT (b,D,T) ----------------
__global__ __launch_bounds__(256) void k_transpose(const float* __restrict__ in, float* __restrict__ out) {
  __shared__ float tile[32][33];
  const int b = blockIdx.z;
  const int d0 = blockIdx.x * 32, t0 = blockIdx.y * 32;
  const int tx = threadIdx.x, ty = threadIdx.y;
  const float* src = in + ((size_t)b * T_ + t0) * D_ + d0;
#pragma unroll
  for (int i = 0; i < 32; i += 8) tile[ty + i][tx] = src[(size_t)(ty + i) * D_ + tx];
  __syncthreads();
  float* dst = out + ((size_t)b * D_ + d0) * T_ + t0;
#pragma unroll
  for (int i = 0; i < 32; i += 8) dst[(size_t)(ty + i) * T_ + tx] = tile[tx][ty + i];
}

// ---------------- 1024-pt real FFT per (b,d) + top-8 bins ----------------
__global__ __launch_bounds__(256) void k_fft_topk(const float* __restrict__ xt, float* __restrict__ comp) {
  __shared__ float2 bA[512], bB[512], tw[256];
  __shared__ float xre[512], xim[512], mag2[512];
  __shared__ float wvv[4];
  __shared__ int wkk[4];
  __shared__ int selk[KSEL];
  const int j = threadIdx.x;
  const int bd = blockIdx.x;
  {
    float ang = -(6.283185307179586f / 512.0f) * (float)j;
    float sn, cs;
    sincosf(ang, &sn, &cs);
    tw[j] = make_float2(cs, sn);
  }
  const float4 v4 = ((const float4*)(xt + (size_t)bd * 1024))[j];
  bA[2 * j] = make_float2(v4.x, v4.y);
  bA[2 * j + 1] = make_float2(v4.z, v4.w);
  __syncthreads();
#pragma unroll
  for (int st = 0; st < 9; ++st) {
    const int s = 1 << st;
    const int p = j >> st;
    const int q = j & (s - 1);
    const int m = 256 >> st;
    float2 a, b2;
    if ((st & 1) == 0) { a = bA[q + s * p]; b2 = bA[q + s * (p + m)]; }
    else               { a = bB[q + s * p]; b2 = bB[q + s * (p + m)]; }
    const float2 w = tw[p << st];
    float2 d0 = make_float2(a.x + b2.x, a.y + b2.y);
    const float ex = a.x - b2.x, ey = a.y - b2.y;
    float2 d1 = make_float2(ex * w.x - ey * w.y, ex * w.y + ey * w.x);
    if ((st & 1) == 0) { bB[q + s * 2 * p] = d0; bB[q + s * (2 * p + 1)] = d1; }
    else               { bA[q + s * 2 * p] = d0; bA[q + s * (2 * p + 1)] = d1; }
    __syncthreads();
  }
#pragma unroll
  for (int u = 0; u < 2; ++u) {
    const int k = (u == 0) ? (j + 1) : (j + 257);
    if (k <= 511) {
      const float2 zk = bB[k & 511];
      const float2 zm = bB[(512 - k) & 511];
      const float Ex = 0.5f * (zk.x + zm.x), Ey = 0.5f * (zk.y - zm.y);
      const float Ox = 0.5f * (zk.y + zm.y), Oy = 0.5f * (zm.x - zk.x);
      float sn, cs;
      sincosf(-(6.283185307179586f / 1024.0f) * (float)k, &sn, &cs);
      const float Xr = Ex + cs * Ox - sn * Oy;
      const float Xi = Ey + cs * Oy + sn * Ox;
      xre[k] = Xr; xim[k] = Xi; mag2[k] = Xr * Xr + Xi * Xi;
    }
  }
  if (j == 0) mag2[0] = -1.0f;
  __syncthreads();
  const int lane = j & 63, wvi = j >> 6;
  for (int r = 0; r < KSEL; ++r) {
    float bv = mag2[j];
    int bk = j;
    const float v2 = mag2[j + 256];
    if (v2 > bv) { bv = v2; bk = j + 256; }
#pragma unroll
    for (int off = 32; off; off >>= 1) {
      const float ov = __shfl_down(bv, off);
      const int ok = __shfl_down(bk, off);
      if (ov > bv || (ov == bv && ok < bk)) { bv = ov; bk = ok; }
    }
    if (lane == 0) { wvv[wvi] = bv; wkk[wvi] = bk; }
    __syncthreads();
    if (j == 0) {
      float fv = wvv[0];
      int fk = wkk[0];
#pragma unroll
      for (int i = 1; i < 4; i++)
        if (wvv[i] > fv || (wvv[i] == fv && wkk[i] < fk)) { fv = wvv[i]; fk = wkk[i]; }
      selk[r] = fk;
      mag2[fk] = -2.0f;
    }
    __syncthreads();
  }
  if (j < KSEL) {
    const int k = selk[j];
    const float re = xre[k], im = xim[k];
    float* o = comp + (size_t)bd * 24 + j * 3;
    o[0] = 2.0f * sqrtf(re * re + im * im) * (1.0f / 1024.0f);
    o[1] = (float)k;
    o[2] = atan2f(im, re);
  }
}

// ---------------- season synthesis + res1 = res - season ----------------
__global__ __launch_bounds__(512) void k_season(const float* __restrict__ comp, const float* __restrict__ res,
                                                float* __restrict__ season, bf16* __restrict__ res1b,
                                                bf16* __restrict__ seasb) {
  const int d = threadIdx.x;
  const int b = blockIdx.y;
  const int t0 = blockIdx.x * 5;
  float a_[8], kf_[8], ph_[8];
  const float* c = comp + ((size_t)b * 512 + d) * 24;
#pragma unroll
  for (int i = 0; i < 8; i++) { a_[i] = c[3 * i]; kf_[i] = c[3 * i + 1]; ph_[i] = c[3 * i + 2]; }
#pragma unroll
  for (int tt = 0; tt < 5; ++tt) {
    const int t = t0 + tt;
    float acc = 0.0f;
#pragma unroll
    for (int i = 0; i < 8; i++) {
      float fr = kf_[i] * (float)t * (1.0f / 1024.0f);
      fr -= floorf(fr);
      acc += a_[i] * __cosf(fmaf(6.283185307179586f, fr, ph_[i]));
    }
    season[((size_t)b * TP + t) * D_ + d] = acc;
    if (t < T_) {
      const float rr = res[((size_t)b * T_ + t) * D_ + d] - acc;
      res1b[((size_t)b * T_ + t) * D_ + d] = __float2bfloat16(rr);
      seasb[((size_t)b * T_ + t) * D_ + d] = __float2bfloat16(acc);
    }
  }
}

// ---------------- fused f32 -> bf16 for all 6 weight tensors ----------------
#define CVT_TOTAL 2686976
__global__ __launch_bounds__(256) void k_cvt_all(const float* __restrict__ s0, const float* __restrict__ s1,
                                                 const float* __restrict__ s2_, const float* __restrict__ s3,
                                                 const float* __restrict__ s4, const float* __restrict__ s5,
                                                 bf16* __restrict__ dst) {
  const int i = (blockIdx.x * 256 + threadIdx.x) * 4;
  if (i >= CVT_TOTAL) return;
  const float* src;
  int off;
  if (i < 262144)       { src = s0;  off = i; }
  else if (i < 524288)  { src = s1;  off = i - 262144; }
  else if (i < 1572864) { src = s2_; off = i - 524288; }
  else if (i < 2621440) { src = s3;  off = i - 1572864; }
  else if (i < 2654208) { src = s4;  off = i - 2621440; }
  else                  { src = s5;  off = i - 2654208; }
  const float4 v = *(const float4*)(src + off);
  bf16* o = dst + i;
  o[0] = __float2bfloat16(v.x); o[1] = __float2bfloat16(v.y);
  o[2] = __float2bfloat16(v.z); o[3] = __float2bfloat16(v.w);
}

// ---------------- growth exp-smooth blocked scan ----------------
__global__ __launch_bounds__(1024) void k_growth_scan2(const float* __restrict__ v, const float* __restrict__ z0,
                                                       const float* __restrict__ sw, const float* __restrict__ v0,
                                                       bf16* __restrict__ s2) {
  const int b = blockIdx.x >> 3;
  const int col = (blockIdx.x & 7) * 64 + (threadIdx.x & 63);
  const int w = threadIdx.x >> 6;
  const float alpha = 1.0f / (1.0f + expf(-sw[col >> 6]));
  const float om = 1.0f - alpha;
  float a64 = alpha;
#pragma unroll
  for (int i = 0; i < 6; i++) a64 *= a64;
  const float* vp = v + (size_t)b * T_ * D_ + col;
  float vprev = (w == 0) ? z0[col] : vp[(size_t)(64 * w - 1) * D_];
  float sloc = 0.0f;
#pragma unroll 8
  for (int j = 0; j < 64; j++) {
    const float nv = vp[(size_t)(64 * w + j) * D_];
    sloc = alpha * sloc + om * (nv - vprev);
    vprev = nv;
  }
  __shared__ float lb[16][64], lc[16][64];
  lb[w][threadIdx.x & 63] = sloc;
  __syncthreads();
  if (w == 0) {
    float s = v0[col];
#pragma unroll
    for (int k = 0; k < 16; k++) { lc[k][threadIdx.x & 63] = s; s = a64 * s + lb[k][threadIdx.x & 63]; }
  }
  __syncthreads();
  float s = lc[w][threadIdx.x & 63];
  vprev = (w == 0) ? z0[col] : vp[(size_t)(64 * w - 1) * D_];
  bf16* op = s2 + (size_t)b * (T_ + 1) * D_ + col;
  if (w == 0) op[0] = __float2bfloat16(v0[col]);
#pragma unroll 8
  for (int j = 0; j < 64; j++) {
    const float nv = vp[(size_t)(64 * w + j) * D_];
    s = alpha * s + om * (nv - vprev);
    vprev = nv;
    op[(size_t)(64 * w + j + 1) * D_] = __float2bfloat16(s);
  }
}

// ---------------- level exp-smooth blocked scan ----------------
__global__ __launch_bounds__(1024) void k_level_scan2(const float* __restrict__ level, const float* __restrict__ gp,
                                                      const float* __restrict__ sp, const float* __restrict__ sw,
                                                      const float* __restrict__ v0, float* __restrict__ out) {
  const int b = blockIdx.x;
  const int w = threadIdx.x >> 6;
  const int c = threadIdx.x & 63;
  const float alpha = 1.0f / (1.0f + expf(-sw[c]));
  const float om = 1.0f - alpha;
  float a64 = alpha;
#pragma unroll
  for (int i = 0; i < 6; i++) a64 *= a64;
  const size_t base = ((size_t)b * T_ + 64 * w) * CO + c;
  float sloc = 0.0f;
#pragma unroll 8
  for (int j = 0; j < 64; j++) {
    const size_t idx = base + (size_t)j * CO;
    const float u = om * (level[idx] - sp[idx]) + alpha * gp[idx];
    out[idx] = u;
    sloc = alpha * sloc + u;
  }
  __shared__ float lb[16][64], lc[16][64];
  lb[w][c] = sloc;
  __syncthreads();
  if (w == 0) {
    float s = v0[c];
#pragma unroll
    for (int k = 0; k < 16; k++) { lc[k][c] = s; s = a64 * s + lb[k][c]; }
  }
  __syncthreads();
  float s = lc[w][c];
#pragma unroll 8
  for (int j = 0; j < 64; j++) {
    const size_t idx = base + (size_t)j * CO;
    s = alpha * s + out[idx];
    out[idx] = s;
  }
}

// ---------------- layer norm over D=512 ----------------
template <int MODE>
__global__ __launch_bounds__(128) void k_ln(const float* __restrict__ x1, const float* __restrict__ x2,
                                            const float* __restrict__ x3, const float* __restrict__ g,
                                            const float* __restrict__ be, float* __restrict__ outF,
                                            bf16* __restrict__ outB) {
  const int m = blockIdx.x, tid = threadIdx.x;
  const int b = m >> 10;
  float4 v = ((const float4*)(x1 + (size_t)m * D_))[tid];
  if (MODE == 0) {
    const float4 se = ((const float4*)(x2 + ((size_t)(m + b * PRED)) * D_))[tid];
    const float4 gr = ((const float4*)(x3 + ((size_t)(m + b + 1)) * D_))[tid];
    v.x -= se.x + gr.x; v.y -= se.y + gr.y; v.z -= se.z + gr.z; v.w -= se.w + gr.w;
  }
  float s = v.x + v.y + v.z + v.w;
  float s2 = v.x * v.x + v.y * v.y + v.z * v.z + v.w * v.w;
#pragma unroll
  for (int off = 32; off; off >>= 1) { s += __shfl_down(s, off); s2 += __shfl_down(s2, off); }
  __shared__ float p1[2], p2[2];
  if ((tid & 63) == 0) { p1[tid >> 6] = s; p2[tid >> 6] = s2; }
  __syncthreads();
  const float S = p1[0] + p1[1], S2 = p2[0] + p2[1];
  const float mu = S * (1.0f / 512.0f);
  const float rs = rsqrtf(fmaxf(S2 * (1.0f / 512.0f) - mu * mu, 0.0f) + 1e-5f);
  const float4 gg = ((const float4*)g)[tid], bb = ((const float4*)be)[tid];
  float4 o;
  o.x = (v.x - mu) * rs * gg.x + bb.x;
  o.y = (v.y - mu) * rs * gg.y + bb.y;
  o.z = (v.z - mu) * rs * gg.z + bb.z;
  o.w = (v.w - mu) * rs * gg.w + bb.w;
  ((float4*)(outF + (size_t)m * D_))[tid] = o;
  if (MODE == 0) {
    bf16* ob = outB + (size_t)m * D_ + tid * 4;
    ob[0] = __float2bfloat16(o.x); ob[1] = __float2bfloat16(o.y);
    ob[2] = __float2bfloat16(o.z); ob[3] = __float2bfloat16(o.w);
  }
}

// ---------------- bf16 MFMA GEMM, swizzled LDS + counted-vmcnt pipeline ----------------
// Wave grid WM x WN (threads = WM*WN*64). One gload_lds16 stages 512/BK rows (RPC).
// LDS swizzle (both-sides; gload dest linear, global source pre-permuted):
//  BK=64: group = 8 rows x 128B; slot cs of row rr holds global chunk (cs ^ rr)
//  BK=32: group = 16 rows; superrow sr = row pair; slot cs holds idx = cs ^ (sr&7)
// K-loop: stage(next); s_waitcnt vmcnt(TLOADS); s_barrier; ds_read+MFMA; s_barrier.
template <int BM, int BN, int BK, int WM, int WN, int EPI>
__global__ __launch_bounds__(WM * WN * 64, 2) void k_gemm(
    const bf16* __restrict__ A, const bf16* __restrict__ Bw,
    const float* __restrict__ bias, float* outF, bf16* __restrict__ outB,
    const float* resid, const int M, const int N, const int K, const int extra) {
  constexpr int NW = WM * WN;
  constexpr int FM = BM / (WM * 16);
  constexpr int FN = BN / (WN * 16);
  constexpr int RPC = 512 / BK;
  constexpr int LA = (BM / RPC) / NW, LB = (BN / RPC) / NW;
  constexpr int KK = BK / 32;
  constexpr int TLOADS = LA + LB;
  static_assert(LA >= 1 && LB >= 1, "tile too small for staging split");
  static_assert((BM / RPC) % NW == 0 && (BN / RPC) % NW == 0, "staging split");
  __shared__ bf16 lsA[2][BM * BK];
  __shared__ bf16 lsB[2][BN * BK];
  const int tid = threadIdx.x;
  const int w = tid >> 6, lane = tid & 63;
  const int tn = blockIdx.x, tm = blockIdx.y;
  const int wr = w / WN, wc = w % WN;
  const int r16 = lane & 15, hi = lane >> 4;

  int srowoff, scoloff;
  if constexpr (BK == 64) {
    const int rr = lane >> 3, cs = lane & 7;
    srowoff = rr;
    scoloff = (cs ^ rr) * 8;
  } else {
    const int sr = lane >> 3, cs = lane & 7;
    const int idx = cs ^ (sr & 7);
    srowoff = sr * 2 + (idx >> 2);
    scoloff = (idx & 3) * 8;
  }

  const f32x4 fzero = {0.f, 0.f, 0.f, 0.f};
  f32x4 acc[FM][FN];
#pragma unroll
  for (int i = 0; i < FM; i++)
#pragma unroll
    for (int jj = 0; jj < FN; jj++) acc[i][jj] = fzero;

  const int NT = K / BK;

  auto stage = [&](int kt, int sel) {
#pragma unroll
    for (int q = 0; q < LA; q++) {
      const int g = w * LA + q;
      int m = tm * BM + g * RPC + srowoff;
      if (m > M - 1) m = M - 1;
      m += (m >> 10) * extra;
      gload_lds16(A + (size_t)m * K + (size_t)kt * BK + scoloff, &lsA[sel][g * 512]);
    }
#pragma unroll
    for (int q = 0; q < LB; q++) {
      const int g = w * LB + q;
      const int n = tn * BN + g * RPC + srowoff;
      gload_lds16(Bw + (size_t)n * K + (size_t)kt * BK + scoloff, &lsB[sel][g * 512]);
    }
  };

  auto frag = [&](const bf16* ls, int row, int cc) -> bf16x8 {
    if constexpr (BK == 64) {
      const int g = row >> 3, rr = row & 7;
      return *(const bf16x8*)&ls[g * 512 + rr * 64 + ((cc ^ rr) << 3)];
    } else {
      const int g = row >> 4, rr = row & 15, sr = rr >> 1;
      const int idx = ((rr & 1) << 2) | cc;
      return *(const bf16x8*)&ls[g * 512 + sr * 64 + ((idx ^ (sr & 7)) << 3)];
    }
  };

  stage(0, 0);
  for (int kt = 0; kt < NT; ++kt) {
    const int sel = kt & 1;
    if (kt + 1 < NT) {
      stage(kt + 1, sel ^ 1);
      vm_wait<TLOADS>();
    } else {
      vm_wait<0>();
    }
    __builtin_amdgcn_sched_barrier(0);
    __builtin_amdgcn_s_barrier();
    __builtin_amdgcn_sched_barrier(0);
#pragma unroll
    for (int kk = 0; kk < KK; ++kk) {
      bf16x8 af[FM], bfv[FN];
#pragma unroll
      for (int i = 0; i < FM; i++)
        af[i] = frag(lsA[sel], wr * (FM * 16) + i * 16 + r16, kk * 4 + hi);
#pragma unroll
      for (int jj = 0; jj < FN; jj++)
        bfv[jj] = frag(lsB[sel], wc * (FN * 16) + jj * 16 + r16, kk * 4 + hi);
#pragma unroll
      for (int i = 0; i < FM; i++)
#pragma unroll
        for (int jj = 0; jj < FN; jj++)
          acc[i][jj] = __builtin_amdgcn_mfma_f32_16x16x32_bf16(af[i], bfv[jj], acc[i][jj], 0, 0, 0);
    }
    if (kt + 1 < NT) {
      __builtin_amdgcn_sched_barrier(0);
      __builtin_amdgcn_s_barrier();
      __builtin_amdgcn_sched_barrier(0);
    }
  }

#pragma unroll
  for (int i = 0; i < FM; i++) {
#pragma unroll
    for (int r = 0; r < 4; r++) {
      const int m = tm * BM + wr * (FM * 16) + i * 16 + hi * 4 + r;
      if (m < M) {
#pragma unroll
        for (int jj = 0; jj < FN; jj++) {
          const int n = tn * BN + wc * (FN * 16) + jj * 16 + r16;
          float x = acc[i][jj][r];
          if (bias) x += bias[n];
          const size_t idx = (size_t)m * N + n;
          if (EPI == 0) {
            outF[idx] = x;
          } else if (EPI == 1) {
            outF[idx] = x;
            outB[idx] = __float2bfloat16(x);
          } else if (EPI == 2) {
            outB[idx] = __float2bfloat16(1.0f / (1.0f + __expf(-x)));
          } else {
            outF[idx] = x + resid[idx];
          }
        }
      }
    }
  }
}

// ---------------- workspace layout ----------------
#define MB (size_t)(1u << 20)
static const size_t OFF_A = 0;
static const size_t OFF_C = 32 * MB;
static const size_t OFF_D = 40 * MB;
static const size_t OFF_E = 48 * MB;
static const size_t OFF_F = 54 * MB;
static const size_t OFF_G = 63 * MB;
static const size_t OFF_H = 72 * MB;
static const size_t OFF_J = 88 * MB;
static const size_t OFF_K = 89 * MB;
static const size_t OFF_K2 = 91 * MB;

#define W_IN 0
#define W_OUT 262144
#define W_FF1 524288
#define W_FF2 1572864
#define W_GW 2621440
#define W_SW2 2654208

extern "C" void kernel_launch(void* const* d_in, const int* in_sizes, int n_in, void* d_out, int out_size,
                              void* d_ws, size_t ws_size, hipStream_t stream) {
  (void)in_sizes; (void)n_in; (void)out_size; (void)ws_size;
  const float* res = (const float*)d_in[0];
  const float* level = (const float*)d_in[1];
  const float* gl_z0 = (const float*)d_in[2];
  const float* gl_in_w = (const float*)d_in[3];
  const float* gl_in_b = (const float*)d_in[4];
  const float* gl_sw = (const float*)d_in[5];
  const float* gl_v0 = (const float*)d_in[6];
  const float* gl_out_w = (const float*)d_in[7];
  const float* gl_out_b = (const float*)d_in[8];
  const float* ll_sw = (const float*)d_in[9];
  const float* ll_v0 = (const float*)d_in[10];
  const float* ll_gw = (const float*)d_in[11];
  const float* ll_gb = (const float*)d_in[12];
  const float* ll_sw2 = (const float*)d_in[13];
  const float* ll_sb = (const float*)d_in[14];
  const float* ff_w1 = (const float*)d_in[15];
  const float* ff_w2 = (const float*)d_in[16];
  const float* n1_g = (const float*)d_in[17];
  const float* n1_b = (const float*)d_in[18];
  const float* n2_g = (const float*)d_in[19];
  const float* n2_b = (const float*)d_in[20];

  char* ws = (char*)d_ws;
  float* resT = (float*)(ws + OFF_A);
  float* vbuf = (float*)(ws + OFF_A);
  bf16* hbuf = (bf16*)(ws + OFF_A);
  bf16* res1b = (bf16*)(ws + OFF_C);
  bf16* res2b = (bf16*)(ws + OFF_C);
  bf16* seasb = (bf16*)(ws + OFF_D);
  bf16* wE = (bf16*)(ws + OFF_E);
  bf16* s2b = (bf16*)(ws + OFF_F);
  bf16* grob = (bf16*)(ws + OFF_G);
  float* res2f = (float*)(ws + OFF_H);
  float* comp = (float*)(ws + OFF_J);
  float* gproj = (float*)(ws + OFF_K);
  float* sproj = (float*)(ws + OFF_K2);

  float* o_res = (float*)d_out;
  float* o_level = o_res + 4194304;
  float* o_growth = o_level + 524288;
  float* o_season = o_growth + 4198400;

  k_transpose<<<dim3(16, 32, 8), dim3(32, 8), 0, stream>>>(res, resT);
  k_fft_topk<<<4096, 256, 0, stream>>>(resT, comp);
  k_season<<<dim3(256, 8), 512, 0, stream>>>(comp, res, o_season, res1b, seasb);
  k_cvt_all<<<(CVT_TOTAL / 4 + 255) / 256, 256, 0, stream>>>(gl_in_w, gl_out_w, ff_w1, ff_w2, ll_gw, ll_sw2, wE);
  // v = res1 @ gl_in_w^T + b   (64x128, BK=64, 4 waves)
  k_gemm<64, 128, 64, 2, 2, 0><<<dim3(4, 128), 256, 0, stream>>>(res1b, wE + W_IN, gl_in_b, vbuf, nullptr, nullptr, 8192, 512, 512, 0);
  k_growth_scan2<<<64, 1024, 0, stream>>>(vbuf, gl_z0, gl_sw, gl_v0, s2b);
  // growth = s2 @ gl_out_w^T + b
  k_gemm<64, 128, 64, 2, 2, 1><<<dim3(4, 129), 256, 0, stream>>>(s2b, wE + W_OUT, gl_out_b, o_growth, grob, nullptr, 8200, 512, 512, 0);
  k_ln<0><<<8192, 128, 0, stream>>>(res, o_season, o_growth, n1_g, n1_b, res2f, res2b);
  // FF1: 256x256, BK=64, 8 waves (512 thr), 128KB LDS, 64 MFMA/wave/iter — high-density 2-phase
  k_gemm<256, 256, 64, 2, 4, 2><<<dim3(8, 32), 512, 0, stream>>>(res2b, wE + W_FF1, nullptr, nullptr, hbuf, nullptr, 8192, 2048, 512, 0);
  // FF2: 64x128, BK=64, K=2048
  k_gemm<64, 128, 64, 2, 2, 3><<<dim3(4, 128), 256, 0, stream>>>(hbuf, wE + W_FF2, nullptr, res2f, nullptr, res2f, 8192, 512, 2048, 0);
  k_ln<1><<<8192, 128, 0, stream>>>(res2f, nullptr, nullptr, n2_g, n2_b, o_res, nullptr);
  // gproj/sproj: 64x64, BK=64, 4 waves (WM=4, WN=1)
  k_gemm<64, 64, 64, 4, 1, 0><<<dim3(1, 128), 256, 0, stream>>>(grob, wE + W_GW, ll_gb, gproj, nullptr, nullptr, 8192, 64, 512, 1);
  k_gemm<64, 64, 64, 4, 1, 0><<<dim3(1, 128), 256, 0, stream>>>(seasb, wE + W_SW2, ll_sb, sproj, nullptr, nullptr, 8192, 64, 512, 0);
  k_level_scan2<<<8, 1024, 0, stream>>>(level, gproj, sproj, ll_sw, ll_v0, o_level);
}

// Round 12
// 219.452 us; speedup vs baseline: 1.2869x; 1.0927x over previous
//
#include <hip/hip_runtime.h>
#include <hip/hip_bf16.h>
#include <math.h>

#define B_ 8
#define T_ 1024
#define D_ 512
#define PRED 256
#define TP (T_ + PRED)
#define NH 8
#define DH 64
#define DFF 2048
#define CO 64
#define KSEL 8

typedef __hip_bfloat16 bf16;
using bf16x8 = __attribute__((ext_vector_type(8))) short;
using f32x4  = __attribute__((ext_vector_type(4))) float;

__device__ __forceinline__ void gload_lds16(const void* gp, void* lp) {
  __builtin_amdgcn_global_load_lds(
      (const __attribute__((address_space(1))) void*)gp,
      (__attribute__((address_space(3))) void*)lp, 16, 0, 0);
}

// counted vmem wait (N = loads allowed to stay in flight)
template <int N>
__device__ __forceinline__ void vm_wait() {
  if constexpr (N == 0)      asm volatile("s_waitcnt vmcnt(0)" ::: "memory");
  else if constexpr (N == 2) asm volatile("s_waitcnt vmcnt(2)" ::: "memory");
  else if constexpr (N == 4) asm volatile("s_waitcnt vmcnt(4)" ::: "memory");
  else if constexpr (N == 6) asm volatile("s_waitcnt vmcnt(6)" ::: "memory");
  else if constexpr (N == 8) asm volatile("s_waitcnt vmcnt(8)" ::: "memory");
  else static_assert(N == 0, "unsupported vmcnt literal");
}

// ---------------- transpose res (b,T,D) -> resT (b,D,T) ----------------
__global__ __launch_bounds__(256) void k_transpose(const float* __restrict__ in, float* __restrict__ out) {
  __shared__ float tile[32][33];
  const int b = blockIdx.z;
  const int d0 = blockIdx.x * 32, t0 = blockIdx.y * 32;
  const int tx = threadIdx.x, ty = threadIdx.y;
  const float* src = in + ((size_t)b * T_ + t0) * D_ + d0;
#pragma unroll
  for (int i = 0; i < 32; i += 8) tile[ty + i][tx] = src[(size_t)(ty + i) * D_ + tx];
  __syncthreads();
  float* dst = out + ((size_t)b * D_ + d0) * T_ + t0;
#pragma unroll
  for (int i = 0; i < 32; i += 8) dst[(size_t)(ty + i) * T_ + tx] = tile[tx][ty + i];
}

// ---------------- 1024-pt real FFT per (b,d) + top-8 bins ----------------
__global__ __launch_bounds__(256) void k_fft_topk(const float* __restrict__ xt, float* __restrict__ comp) {
  __shared__ float2 bA[512], bB[512], tw[256];
  __shared__ float xre[512], xim[512], mag2[512];
  __shared__ float wvv[4];
  __shared__ int wkk[4];
  __shared__ int selk[KSEL];
  const int j = threadIdx.x;
  const int bd = blockIdx.x;
  {
    float ang = -(6.283185307179586f / 512.0f) * (float)j;
    float sn, cs;
    sincosf(ang, &sn, &cs);
    tw[j] = make_float2(cs, sn);
  }
  const float4 v4 = ((const float4*)(xt + (size_t)bd * 1024))[j];
  bA[2 * j] = make_float2(v4.x, v4.y);
  bA[2 * j + 1] = make_float2(v4.z, v4.w);
  __syncthreads();
#pragma unroll
  for (int st = 0; st < 9; ++st) {
    const int s = 1 << st;
    const int p = j >> st;
    const int q = j & (s - 1);
    const int m = 256 >> st;
    float2 a, b2;
    if ((st & 1) == 0) { a = bA[q + s * p]; b2 = bA[q + s * (p + m)]; }
    else               { a = bB[q + s * p]; b2 = bB[q + s * (p + m)]; }
    const float2 w = tw[p << st];
    float2 d0 = make_float2(a.x + b2.x, a.y + b2.y);
    const float ex = a.x - b2.x, ey = a.y - b2.y;
    float2 d1 = make_float2(ex * w.x - ey * w.y, ex * w.y + ey * w.x);
    if ((st & 1) == 0) { bB[q + s * 2 * p] = d0; bB[q + s * (2 * p + 1)] = d1; }
    else               { bA[q + s * 2 * p] = d0; bA[q + s * (2 * p + 1)] = d1; }
    __syncthreads();
  }
#pragma unroll
  for (int u = 0; u < 2; ++u) {
    const int k = (u == 0) ? (j + 1) : (j + 257);
    if (k <= 511) {
      const float2 zk = bB[k & 511];
      const float2 zm = bB[(512 - k) & 511];
      const float Ex = 0.5f * (zk.x + zm.x), Ey = 0.5f * (zk.y - zm.y);
      const float Ox = 0.5f * (zk.y + zm.y), Oy = 0.5f * (zm.x - zk.x);
      float sn, cs;
      sincosf(-(6.283185307179586f / 1024.0f) * (float)k, &sn, &cs);
      const float Xr = Ex + cs * Ox - sn * Oy;
      const float Xi = Ey + cs * Oy + sn * Ox;
      xre[k] = Xr; xim[k] = Xi; mag2[k] = Xr * Xr + Xi * Xi;
    }
  }
  if (j == 0) mag2[0] = -1.0f;
  __syncthreads();
  const int lane = j & 63, wvi = j >> 6;
  for (int r = 0; r < KSEL; ++r) {
    float bv = mag2[j];
    int bk = j;
    const float v2 = mag2[j + 256];
    if (v2 > bv) { bv = v2; bk = j + 256; }
#pragma unroll
    for (int off = 32; off; off >>= 1) {
      const float ov = __shfl_down(bv, off);
      const int ok = __shfl_down(bk, off);
      if (ov > bv || (ov == bv && ok < bk)) { bv = ov; bk = ok; }
    }
    if (lane == 0) { wvv[wvi] = bv; wkk[wvi] = bk; }
    __syncthreads();
    if (j == 0) {
      float fv = wvv[0];
      int fk = wkk[0];
#pragma unroll
      for (int i = 1; i < 4; i++)
        if (wvv[i] > fv || (wvv[i] == fv && wkk[i] < fk)) { fv = wvv[i]; fk = wkk[i]; }
      selk[r] = fk;
      mag2[fk] = -2.0f;
    }
    __syncthreads();
  }
  if (j < KSEL) {
    const int k = selk[j];
    const float re = xre[k], im = xim[k];
    float* o = comp + (size_t)bd * 24 + j * 3;
    o[0] = 2.0f * sqrtf(re * re + im * im) * (1.0f / 1024.0f);
    o[1] = (float)k;
    o[2] = atan2f(im, re);
  }
}

// ---------------- season synthesis + res1 = res - season ----------------
__global__ __launch_bounds__(512) void k_season(const float* __restrict__ comp, const float* __restrict__ res,
                                                float* __restrict__ season, bf16* __restrict__ res1b,
                                                bf16* __restrict__ seasb) {
  const int d = threadIdx.x;
  const int b = blockIdx.y;
  const int t0 = blockIdx.x * 5;
  float a_[8], kf_[8], ph_[8];
  const float* c = comp + ((size_t)b * 512 + d) * 24;
#pragma unroll
  for (int i = 0; i < 8; i++) { a_[i] = c[3 * i]; kf_[i] = c[3 * i + 1]; ph_[i] = c[3 * i + 2]; }
#pragma unroll
  for (int tt = 0; tt < 5; ++tt) {
    const int t = t0 + tt;
    float acc = 0.0f;
#pragma unroll
    for (int i = 0; i < 8; i++) {
      float fr = kf_[i] * (float)t * (1.0f / 1024.0f);
      fr -= floorf(fr);
      acc += a_[i] * __cosf(fmaf(6.283185307179586f, fr, ph_[i]));
    }
    season[((size_t)b * TP + t) * D_ + d] = acc;
    if (t < T_) {
      const float rr = res[((size_t)b * T_ + t) * D_ + d] - acc;
      res1b[((size_t)b * T_ + t) * D_ + d] = __float2bfloat16(rr);
      seasb[((size_t)b * T_ + t) * D_ + d] = __float2bfloat16(acc);
    }
  }
}

// ---------------- fused f32 -> bf16 for all 6 weight tensors ----------------
#define CVT_TOTAL 2686976
__global__ __launch_bounds__(256) void k_cvt_all(const float* __restrict__ s0, const float* __restrict__ s1,
                                                 const float* __restrict__ s2_, const float* __restrict__ s3,
                                                 const float* __restrict__ s4, const float* __restrict__ s5,
                                                 bf16* __restrict__ dst) {
  const int i = (blockIdx.x * 256 + threadIdx.x) * 4;
  if (i >= CVT_TOTAL) return;
  const float* src;
  int off;
  if (i < 262144)       { src = s0;  off = i; }
  else if (i < 524288)  { src = s1;  off = i - 262144; }
  else if (i < 1572864) { src = s2_; off = i - 524288; }
  else if (i < 2621440) { src = s3;  off = i - 1572864; }
  else if (i < 2654208) { src = s4;  off = i - 2621440; }
  else                  { src = s5;  off = i - 2654208; }
  const float4 v = *(const float4*)(src + off);
  bf16* o = dst + i;
  o[0] = __float2bfloat16(v.x); o[1] = __float2bfloat16(v.y);
  o[2] = __float2bfloat16(v.z); o[3] = __float2bfloat16(v.w);
}

// ---------------- growth exp-smooth blocked scan ----------------
__global__ __launch_bounds__(1024) void k_growth_scan2(const float* __restrict__ v, const float* __restrict__ z0,
                                                       const float* __restrict__ sw, const float* __restrict__ v0,
                                                       bf16* __restrict__ s2) {
  const int b = blockIdx.x >> 3;
  const int col = (blockIdx.x & 7) * 64 + (threadIdx.x & 63);
  const int w = threadIdx.x >> 6;
  const float alpha = 1.0f / (1.0f + expf(-sw[col >> 6]));
  const float om = 1.0f - alpha;
  float a64 = alpha;
#pragma unroll
  for (int i = 0; i < 6; i++) a64 *= a64;
  const float* vp = v + (size_t)b * T_ * D_ + col;
  float vprev = (w == 0) ? z0[col] : vp[(size_t)(64 * w - 1) * D_];
  float sloc = 0.0f;
#pragma unroll 8
  for (int j = 0; j < 64; j++) {
    const float nv = vp[(size_t)(64 * w + j) * D_];
    sloc = alpha * sloc + om * (nv - vprev);
    vprev = nv;
  }
  __shared__ float lb[16][64], lc[16][64];
  lb[w][threadIdx.x & 63] = sloc;
  __syncthreads();
  if (w == 0) {
    float s = v0[col];
#pragma unroll
    for (int k = 0; k < 16; k++) { lc[k][threadIdx.x & 63] = s; s = a64 * s + lb[k][threadIdx.x & 63]; }
  }
  __syncthreads();
  float s = lc[w][threadIdx.x & 63];
  vprev = (w == 0) ? z0[col] : vp[(size_t)(64 * w - 1) * D_];
  bf16* op = s2 + (size_t)b * (T_ + 1) * D_ + col;
  if (w == 0) op[0] = __float2bfloat16(v0[col]);
#pragma unroll 8
  for (int j = 0; j < 64; j++) {
    const float nv = vp[(size_t)(64 * w + j) * D_];
    s = alpha * s + om * (nv - vprev);
    vprev = nv;
    op[(size_t)(64 * w + j + 1) * D_] = __float2bfloat16(s);
  }
}

// ---------------- level exp-smooth blocked scan ----------------
__global__ __launch_bounds__(1024) void k_level_scan2(const float* __restrict__ level, const float* __restrict__ gp,
                                                      const float* __restrict__ sp, const float* __restrict__ sw,
                                                      const float* __restrict__ v0, float* __restrict__ out) {
  const int b = blockIdx.x;
  const int w = threadIdx.x >> 6;
  const int c = threadIdx.x & 63;
  const float alpha = 1.0f / (1.0f + expf(-sw[c]));
  const float om = 1.0f - alpha;
  float a64 = alpha;
#pragma unroll
  for (int i = 0; i < 6; i++) a64 *= a64;
  const size_t base = ((size_t)b * T_ + 64 * w) * CO + c;
  float sloc = 0.0f;
#pragma unroll 8
  for (int j = 0; j < 64; j++) {
    const size_t idx = base + (size_t)j * CO;
    const float u = om * (level[idx] - sp[idx]) + alpha * gp[idx];
    out[idx] = u;
    sloc = alpha * sloc + u;
  }
  __shared__ float lb[16][64], lc[16][64];
  lb[w][c] = sloc;
  __syncthreads();
  if (w == 0) {
    float s = v0[c];
#pragma unroll
    for (int k = 0; k < 16; k++) { lc[k][c] = s; s = a64 * s + lb[k][c]; }
  }
  __syncthreads();
  float s = lc[w][c];
#pragma unroll 8
  for (int j = 0; j < 64; j++) {
    const size_t idx = base + (size_t)j * CO;
    s = alpha * s + out[idx];
    out[idx] = s;
  }
}

// ---------------- layer norm over D=512 ----------------
template <int MODE>
__global__ __launch_bounds__(128) void k_ln(const float* __restrict__ x1, const float* __restrict__ x2,
                                            const float* __restrict__ x3, const float* __restrict__ g,
                                            const float* __restrict__ be, float* __restrict__ outF,
                                            bf16* __restrict__ outB) {
  const int m = blockIdx.x, tid = threadIdx.x;
  const int b = m >> 10;
  float4 v = ((const float4*)(x1 + (size_t)m * D_))[tid];
  if (MODE == 0) {
    const float4 se = ((const float4*)(x2 + ((size_t)(m + b * PRED)) * D_))[tid];
    const float4 gr = ((const float4*)(x3 + ((size_t)(m + b + 1)) * D_))[tid];
    v.x -= se.x + gr.x; v.y -= se.y + gr.y; v.z -= se.z + gr.z; v.w -= se.w + gr.w;
  }
  float s = v.x + v.y + v.z + v.w;
  float s2 = v.x * v.x + v.y * v.y + v.z * v.z + v.w * v.w;
#pragma unroll
  for (int off = 32; off; off >>= 1) { s += __shfl_down(s, off); s2 += __shfl_down(s2, off); }
  __shared__ float p1[2], p2[2];
  if ((tid & 63) == 0) { p1[tid >> 6] = s; p2[tid >> 6] = s2; }
  __syncthreads();
  const float S = p1[0] + p1[1], S2 = p2[0] + p2[1];
  const float mu = S * (1.0f / 512.0f);
  const float rs = rsqrtf(fmaxf(S2 * (1.0f / 512.0f) - mu * mu, 0.0f) + 1e-5f);
  const float4 gg = ((const float4*)g)[tid], bb = ((const float4*)be)[tid];
  float4 o;
  o.x = (v.x - mu) * rs * gg.x + bb.x;
  o.y = (v.y - mu) * rs * gg.y + bb.y;
  o.z = (v.z - mu) * rs * gg.z + bb.z;
  o.w = (v.w - mu) * rs * gg.w + bb.w;
  ((float4*)(outF + (size_t)m * D_))[tid] = o;
  if (MODE == 0) {
    bf16* ob = outB + (size_t)m * D_ + tid * 4;
    ob[0] = __float2bfloat16(o.x); ob[1] = __float2bfloat16(o.y);
    ob[2] = __float2bfloat16(o.z); ob[3] = __float2bfloat16(o.w);
  }
}

// ---------------- bf16 MFMA GEMM, swizzled LDS + counted-vmcnt pipeline ----------------
// tm = blockIdx.x (FASTEST dispatch index): same-tm blocks (sharing the A row-panel)
// get dispatch ids congruent mod NXCD -> co-locate on one XCD's L2 (A staged as L2 hit).
// Wave grid WM x WN (threads = WM*WN*64). One gload_lds16 stages 512/BK rows (RPC).
// LDS swizzle (both-sides; gload dest linear, global source pre-permuted):
//  BK=64: group = 8 rows x 128B; slot cs of row rr holds global chunk (cs ^ rr)
//  BK=32: group = 16 rows; superrow sr = row pair; slot cs holds idx = cs ^ (sr&7)
// K-loop: stage(next); s_waitcnt vmcnt(TLOADS); s_barrier; ds_read+MFMA; s_barrier.
// DUAL: blockIdx.z==1 switches to a second (A,B,bias,out,extra) problem of same shape.
template <int BM, int BN, int BK, int WM, int WN, int EPI, bool DUAL = false>
__global__ __launch_bounds__(WM * WN * 64, 2) void k_gemm(
    const bf16* __restrict__ A, const bf16* __restrict__ Bw,
    const float* __restrict__ bias, float* outF, bf16* __restrict__ outB,
    const float* resid, const int M, const int N, const int K, int extra,
    const bf16* __restrict__ A2, const bf16* __restrict__ Bw2,
    const float* __restrict__ bias2, float* outF2, int extra2) {
  constexpr int NW = WM * WN;
  constexpr int FM = BM / (WM * 16);
  constexpr int FN = BN / (WN * 16);
  constexpr int RPC = 512 / BK;
  constexpr int LA = (BM / RPC) / NW, LB = (BN / RPC) / NW;
  constexpr int KK = BK / 32;
  constexpr int TLOADS = LA + LB;
  static_assert(LA >= 1 && LB >= 1, "tile too small for staging split");
  static_assert((BM / RPC) % NW == 0 && (BN / RPC) % NW == 0, "staging split");
  if constexpr (DUAL) {
    if (blockIdx.z == 1) { A = A2; Bw = Bw2; bias = bias2; outF = outF2; extra = extra2; }
  }
  __shared__ bf16 lsA[2][BM * BK];
  __shared__ bf16 lsB[2][BN * BK];
  const int tid = threadIdx.x;
  const int w = tid >> 6, lane = tid & 63;
  const int tm = blockIdx.x, tn = blockIdx.y;   // tm fastest -> XCD A-locality
  const int wr = w / WN, wc = w % WN;
  const int r16 = lane & 15, hi = lane >> 4;

  int srowoff, scoloff;
  if constexpr (BK == 64) {
    const int rr = lane >> 3, cs = lane & 7;
    srowoff = rr;
    scoloff = (cs ^ rr) * 8;
  } else {
    const int sr = lane >> 3, cs = lane & 7;
    const int idx = cs ^ (sr & 7);
    srowoff = sr * 2 + (idx >> 2);
    scoloff = (idx & 3) * 8;
  }

  const f32x4 fzero = {0.f, 0.f, 0.f, 0.f};
  f32x4 acc[FM][FN];
#pragma unroll
  for (int i = 0; i < FM; i++)
#pragma unroll
    for (int jj = 0; jj < FN; jj++) acc[i][jj] = fzero;

  const int NT = K / BK;

  auto stage = [&](int kt, int sel) {
#pragma unroll
    for (int q = 0; q < LA; q++) {
      const int g = w * LA + q;
      int m = tm * BM + g * RPC + srowoff;
      if (m > M - 1) m = M - 1;
      m += (m >> 10) * extra;
      gload_lds16(A + (size_t)m * K + (size_t)kt * BK + scoloff, &lsA[sel][g * 512]);
    }
#pragma unroll
    for (int q = 0; q < LB; q++) {
      const int g = w * LB + q;
      const int n = tn * BN + g * RPC + srowoff;
      gload_lds16(Bw + (size_t)n * K + (size_t)kt * BK + scoloff, &lsB[sel][g * 512]);
    }
  };

  auto frag = [&](const bf16* ls, int row, int cc) -> bf16x8 {
    if constexpr (BK == 64) {
      const int g = row >> 3, rr = row & 7;
      return *(const bf16x8*)&ls[g * 512 + rr * 64 + ((cc ^ rr) << 3)];
    } else {
      const int g = row >> 4, rr = row & 15, sr = rr >> 1;
      const int idx = ((rr & 1) << 2) | cc;
      return *(const bf16x8*)&ls[g * 512 + sr * 64 + ((idx ^ (sr & 7)) << 3)];
    }
  };

  stage(0, 0);
  for (int kt = 0; kt < NT; ++kt) {
    const int sel = kt & 1;
    if (kt + 1 < NT) {
      stage(kt + 1, sel ^ 1);
      vm_wait<TLOADS>();
    } else {
      vm_wait<0>();
    }
    __builtin_amdgcn_sched_barrier(0);
    __builtin_amdgcn_s_barrier();
    __builtin_amdgcn_sched_barrier(0);
#pragma unroll
    for (int kk = 0; kk < KK; ++kk) {
      bf16x8 af[FM], bfv[FN];
#pragma unroll
      for (int i = 0; i < FM; i++)
        af[i] = frag(lsA[sel], wr * (FM * 16) + i * 16 + r16, kk * 4 + hi);
#pragma unroll
      for (int jj = 0; jj < FN; jj++)
        bfv[jj] = frag(lsB[sel], wc * (FN * 16) + jj * 16 + r16, kk * 4 + hi);
#pragma unroll
      for (int i = 0; i < FM; i++)
#pragma unroll
        for (int jj = 0; jj < FN; jj++)
          acc[i][jj] = __builtin_amdgcn_mfma_f32_16x16x32_bf16(af[i], bfv[jj], acc[i][jj], 0, 0, 0);
    }
    if (kt + 1 < NT) {
      __builtin_amdgcn_sched_barrier(0);
      __builtin_amdgcn_s_barrier();
      __builtin_amdgcn_sched_barrier(0);
    }
  }

#pragma unroll
  for (int i = 0; i < FM; i++) {
#pragma unroll
    for (int r = 0; r < 4; r++) {
      const int m = tm * BM + wr * (FM * 16) + i * 16 + hi * 4 + r;
      if (m < M) {
#pragma unroll
        for (int jj = 0; jj < FN; jj++) {
          const int n = tn * BN + wc * (FN * 16) + jj * 16 + r16;
          float x = acc[i][jj][r];
          if (bias) x += bias[n];
          const size_t idx = (size_t)m * N + n;
          if (EPI == 0) {
            outF[idx] = x;
          } else if (EPI == 1) {
            outF[idx] = x;
            outB[idx] = __float2bfloat16(x);
          } else if (EPI == 2) {
            outB[idx] = __float2bfloat16(1.0f / (1.0f + __expf(-x)));
          } else {
            outF[idx] = x + resid[idx];
          }
        }
      }
    }
  }
}

// ---------------- workspace layout ----------------
#define MB (size_t)(1u << 20)
static const size_t OFF_A = 0;
static const size_t OFF_C = 32 * MB;
static const size_t OFF_D = 40 * MB;
static const size_t OFF_E = 48 * MB;
static const size_t OFF_F = 54 * MB;
static const size_t OFF_G = 63 * MB;
static const size_t OFF_H = 72 * MB;
static const size_t OFF_J = 88 * MB;
static const size_t OFF_K = 89 * MB;
static const size_t OFF_K2 = 91 * MB;

#define W_IN 0
#define W_OUT 262144
#define W_FF1 524288
#define W_FF2 1572864
#define W_GW 2621440
#define W_SW2 2654208

extern "C" void kernel_launch(void* const* d_in, const int* in_sizes, int n_in, void* d_out, int out_size,
                              void* d_ws, size_t ws_size, hipStream_t stream) {
  (void)in_sizes; (void)n_in; (void)out_size; (void)ws_size;
  const float* res = (const float*)d_in[0];
  const float* level = (const float*)d_in[1];
  const float* gl_z0 = (const float*)d_in[2];
  const float* gl_in_w = (const float*)d_in[3];
  const float* gl_in_b = (const float*)d_in[4];
  const float* gl_sw = (const float*)d_in[5];
  const float* gl_v0 = (const float*)d_in[6];
  const float* gl_out_w = (const float*)d_in[7];
  const float* gl_out_b = (const float*)d_in[8];
  const float* ll_sw = (const float*)d_in[9];
  const float* ll_v0 = (const float*)d_in[10];
  const float* ll_gw = (const float*)d_in[11];
  const float* ll_gb = (const float*)d_in[12];
  const float* ll_sw2 = (const float*)d_in[13];
  const float* ll_sb = (const float*)d_in[14];
  const float* ff_w1 = (const float*)d_in[15];
  const float* ff_w2 = (const float*)d_in[16];
  const float* n1_g = (const float*)d_in[17];
  const float* n1_b = (const float*)d_in[18];
  const float* n2_g = (const float*)d_in[19];
  const float* n2_b = (const float*)d_in[20];

  char* ws = (char*)d_ws;
  float* resT = (float*)(ws + OFF_A);
  float* vbuf = (float*)(ws + OFF_A);
  bf16* hbuf = (bf16*)(ws + OFF_A);
  bf16* res1b = (bf16*)(ws + OFF_C);
  bf16* res2b = (bf16*)(ws + OFF_C);
  bf16* seasb = (bf16*)(ws + OFF_D);
  bf16* wE = (bf16*)(ws + OFF_E);
  bf16* s2b = (bf16*)(ws + OFF_F);
  bf16* grob = (bf16*)(ws + OFF_G);
  float* res2f = (float*)(ws + OFF_H);
  float* comp = (float*)(ws + OFF_J);
  float* gproj = (float*)(ws + OFF_K);
  float* sproj = (float*)(ws + OFF_K2);

  float* o_res = (float*)d_out;
  float* o_level = o_res + 4194304;
  float* o_growth = o_level + 524288;
  float* o_season = o_growth + 4198400;

  k_transpose<<<dim3(16, 32, 8), dim3(32, 8), 0, stream>>>(res, resT);
  k_fft_topk<<<4096, 256, 0, stream>>>(resT, comp);
  k_season<<<dim3(256, 8), 512, 0, stream>>>(comp, res, o_season, res1b, seasb);
  k_cvt_all<<<(CVT_TOTAL / 4 + 255) / 256, 256, 0, stream>>>(gl_in_w, gl_out_w, ff_w1, ff_w2, ll_gw, ll_sw2, wE);
  // v = res1 @ gl_in_w^T + b   (64x128, BK=64, 4 waves; tm-fastest grid)
  k_gemm<64, 128, 64, 2, 2, 0><<<dim3(128, 4), 256, 0, stream>>>(
      res1b, wE + W_IN, gl_in_b, vbuf, nullptr, nullptr, 8192, 512, 512, 0,
      nullptr, nullptr, nullptr, nullptr, 0);
  k_growth_scan2<<<64, 1024, 0, stream>>>(vbuf, gl_z0, gl_sw, gl_v0, s2b);
  // growth = s2 @ gl_out_w^T + b
  k_gemm<64, 128, 64, 2, 2, 1><<<dim3(129, 4), 256, 0, stream>>>(
      s2b, wE + W_OUT, gl_out_b, o_growth, grob, nullptr, 8200, 512, 512, 0,
      nullptr, nullptr, nullptr, nullptr, 0);
  k_ln<0><<<8192, 128, 0, stream>>>(res, o_season, o_growth, n1_g, n1_b, res2f, res2b);
  // FF1: 128x128 BK=32, 4 waves (best measured config), tm-fastest grid
  k_gemm<128, 128, 32, 2, 2, 2><<<dim3(64, 16), 256, 0, stream>>>(
      res2b, wE + W_FF1, nullptr, nullptr, hbuf, nullptr, 8192, 2048, 512, 0,
      nullptr, nullptr, nullptr, nullptr, 0);
  // FF2: 64x128 BK=64, K=2048
  k_gemm<64, 128, 64, 2, 2, 3><<<dim3(128, 4), 256, 0, stream>>>(
      hbuf, wE + W_FF2, nullptr, res2f, nullptr, res2f, 8192, 512, 2048, 0,
      nullptr, nullptr, nullptr, nullptr, 0);
  k_ln<1><<<8192, 128, 0, stream>>>(res2f, nullptr, nullptr, n2_g, n2_b, o_res, nullptr);
  // gproj & sproj merged: one dual dispatch (z=0: growth@ll_gw; z=1: season@ll_sw2)
  k_gemm<64, 64, 64, 4, 1, 0, true><<<dim3(128, 1, 2), 256, 0, stream>>>(
      grob, wE + W_GW, ll_gb, gproj, nullptr, nullptr, 8192, 64, 512, 1,
      seasb, wE + W_SW2, ll_sb, sproj, 0);
  k_level_scan2<<<8, 1024, 0, stream>>>(level, gproj, sproj, ll_sw, ll_v0, o_level);
}